// Round 4
// baseline (155.812 us; speedup 1.0000x reference)
//
#include <hip/hip_runtime.h>
#include <math.h>

#define KEXP 7
#define DDIM 1024
#define RDIM 128
#define TSEQ 2048
#define BBATCH 4
#define TAU_C 1.2f
#define EPS_C 1e-9f
#define LN_EPS_C 1e-5f

// ws layout: int flags[64] (256 B), then floats:
#define WS_S     64                   // s[b][k][1024]   : 28672 floats
#define WS_BASIS (64 + 28672)         // basis[b][128]   : 512
#define WS_W     (WS_BASIS + 512)     // w[b][8]         : 32
#define WS_PSTAT (WS_W + 32)          // pstat[b][k][16][2] : 896

#define NCHUNK 512                    // 8192 rows / 16 rows-per-chunk

__device__ __forceinline__ float dot4(float4 a, float4 b) {
    return fmaf(a.x, b.x, fmaf(a.y, b.y, fmaf(a.z, b.z, a.w * b.w)));
}

__device__ __forceinline__ void arrive(int* flags, int idx) {
    // call from tid 0 only, after __syncthreads()
    __threadfence();
    __hip_atomic_fetch_add(&flags[idx], 1, __ATOMIC_RELEASE, __HIP_MEMORY_SCOPE_AGENT);
}

__device__ __forceinline__ void wait_flag(int* flags, int idx, int target, int tid) {
    if (tid == 0) {
        while (__hip_atomic_load(&flags[idx], __ATOMIC_ACQUIRE, __HIP_MEMORY_SCOPE_AGENT) < target)
            __builtin_amdgcn_s_sleep(2);
    }
    __syncthreads();
}

__global__ __launch_bounds__(256, 3) void k_mega(const float* __restrict__ h,
                                                 const float* __restrict__ gate_w,
                                                 const float* __restrict__ gate_b,
                                                 const float* __restrict__ U_w,
                                                 const float* __restrict__ V,
                                                 const float* __restrict__ ln_g,
                                                 const float* __restrict__ ln_b,
                                                 const float* __restrict__ comp_w,
                                                 const float* __restrict__ comp_b,
                                                 float* __restrict__ G,
                                                 float* __restrict__ out,
                                                 float* __restrict__ ws) {
    int* flags = (int*)ws;
    const int bid = blockIdx.x;
    const int tid = threadIdx.x;
    const int lane = tid & 63;
    const int wv = tid >> 6;

    __shared__ float sA[512];
    __shared__ float4 sB[1024];
    __shared__ int sChunk;

    // ======================= role phase =======================
    if (bid < 32) {
        // ---- basis: basis[b][r] = h_last . U_w[r], 16 r's per block
        const int b = bid >> 3;
        const int chunk = bid & 7;
        const float4* h4 = (const float4*)(h + ((size_t)b * TSEQ + (TSEQ - 1)) * DDIM);
        float4 hf[4];
#pragma unroll
        for (int j = 0; j < 4; ++j) hf[j] = h4[j * 64 + lane];
        const int r0 = chunk * 16 + wv * 4;
        float part[4];
#pragma unroll
        for (int rr = 0; rr < 4; ++rr) {
            const float4* u4 = (const float4*)(U_w + (size_t)(r0 + rr) * DDIM);
            float a = 0.f;
#pragma unroll
            for (int j = 0; j < 4; ++j) a += dot4(hf[j], u4[j * 64 + lane]);
            part[rr] = a;
        }
#pragma unroll
        for (int off = 32; off > 0; off >>= 1)
#pragma unroll
            for (int rr = 0; rr < 4; ++rr)
                part[rr] += __shfl_xor(part[rr], off, 64);
        if (lane == 0) {
#pragma unroll
            for (int rr = 0; rr < 4; ++rr)
                ws[WS_BASIS + b * RDIM + r0 + rr] = part[rr];
        }
        __syncthreads();
        if (tid == 0) arrive(flags, 0);
    } else if (bid < 36) {
        // ---- weights: leftover weights for batch b
        const int b = bid - 32;
        const float4* h4 = (const float4*)(h + ((size_t)b * TSEQ + (TSEQ - 1)) * DDIM);
        for (int e = wv; e < KEXP; e += 4) {
            const float4* gw4 = (const float4*)(gate_w + (size_t)e * DDIM);
            float a = 0.f;
#pragma unroll
            for (int j = 0; j < 4; ++j) a += dot4(h4[j * 64 + lane], gw4[j * 64 + lane]);
#pragma unroll
            for (int off = 32; off > 0; off >>= 1) a += __shfl_xor(a, off, 64);
            if (lane == 0) sA[e] = a + gate_b[e];
        }
        __syncthreads();
        if (tid == 0) {
            float l0[KEXP], m0 = -1e30f;
#pragma unroll
            for (int j = 0; j < KEXP; ++j) { l0[j] = sA[j]; m0 = fmaxf(m0, l0[j]); }
            float es0 = 0.f, g[KEXP];
#pragma unroll
            for (int j = 0; j < KEXP; ++j) { g[j] = expf(l0[j] - m0); es0 += g[j]; }
            const float inv0 = 1.f / es0;
#pragma unroll
            for (int j = 0; j < KEXP; ++j) g[j] *= inv0;
            int i1 = 0;
            for (int j = 1; j < KEXP; ++j) if (g[j] > g[i1]) i1 = j;
            int i2 = -1;
            for (int j = 0; j < KEXP; ++j)
                if (j != i1 && (i2 < 0 || g[j] > g[i2])) i2 = j;
            int i3 = -1;
            for (int j = 0; j < KEXP; ++j)
                if (j != i1 && j != i2 && (i3 < 0 || g[j] > g[i3])) i3 = j;
            int i4 = -1;
            for (int j = 0; j < KEXP; ++j)
                if (j != i1 && j != i2 && j != i3 && (i4 < 0 || g[j] > g[i4])) i4 = j;
            float s = fmaxf(g[i3] + g[i4], EPS_C);
            float p[KEXP];
#pragma unroll
            for (int j = 0; j < KEXP; ++j) p[j] = 0.f;
            p[i3] = g[i3] / s;
            p[i4] = g[i4] / s;
            float l[KEXP], m = -1e30f;
#pragma unroll
            for (int j = 0; j < KEXP; ++j) {
                l[j] = logf(fmaxf(p[j], EPS_C)) * (1.f / TAU_C);
                m = fmaxf(m, l[j]);
            }
            float es = 0.f, w[KEXP];
#pragma unroll
            for (int j = 0; j < KEXP; ++j) { w[j] = expf(l[j] - m); es += w[j]; }
            const float inv = 1.f / es;
            float wsum = 0.f;
#pragma unroll
            for (int j = 0; j < KEXP; ++j) { w[j] *= inv; wsum += w[j]; ws[WS_W + b * 8 + j] = w[j]; }
            ws[WS_W + b * 8 + 7] = wsum;
            arrive(flags, 0);
        }
    } else if (bid < 148) {
        // ---- sv: s[b][k][64-d chunk] for all b, + partial LN stats
        wait_flag(flags, 0, 36, tid);
        const int idx = bid - 36;
        const int k = idx >> 4;
        const int chunk = idx & 15;
        const int col = tid & 15;
        const int rc = tid >> 4;

        sA[tid] = ws[WS_BASIS + tid];
        sA[tid + 256] = ws[WS_BASIS + tid + 256];
        __syncthreads();

        const float4* V4 = (const float4*)(V + (size_t)k * RDIM * DDIM);
        float4 acc[BBATCH];
#pragma unroll
        for (int b = 0; b < BBATCH; ++b) acc[b] = make_float4(0.f, 0.f, 0.f, 0.f);
#pragma unroll
        for (int rr = 0; rr < 8; ++rr) {
            const int r = rc * 8 + rr;
            float4 v = V4[(size_t)r * 256 + chunk * 16 + col];
#pragma unroll
            for (int b = 0; b < BBATCH; ++b) {
                const float br = sA[b * RDIM + r];
                acc[b].x = fmaf(br, v.x, acc[b].x);
                acc[b].y = fmaf(br, v.y, acc[b].y);
                acc[b].z = fmaf(br, v.z, acc[b].z);
                acc[b].w = fmaf(br, v.w, acc[b].w);
            }
        }
#pragma unroll
        for (int b = 0; b < BBATCH; ++b) sB[(rc * 4 + b) * 16 + col] = acc[b];
        __syncthreads();

        if (tid < 64) {
            const int b = tid >> 4;
            const int c = tid & 15;
            float4 s4 = make_float4(0.f, 0.f, 0.f, 0.f);
#pragma unroll
            for (int q = 0; q < 16; ++q) {
                float4 p = sB[(q * 4 + b) * 16 + c];
                s4.x += p.x; s4.y += p.y; s4.z += p.z; s4.w += p.w;
            }
            ((float4*)(ws + WS_S))[(size_t)(b * KEXP + k) * 256 + chunk * 16 + c] = s4;
            float p1 = s4.x + s4.y + s4.z + s4.w;
            float p2 = dot4(s4, s4);
#pragma unroll
            for (int off = 8; off > 0; off >>= 1) {
                p1 += __shfl_xor(p1, off, 64);
                p2 += __shfl_xor(p2, off, 64);
            }
            if (c == 0) {
                ws[WS_PSTAT + ((b * KEXP + k) * 16 + chunk) * 2 + 0] = p1;
                ws[WS_PSTAT + ((b * KEXP + k) * 16 + chunk) * 2 + 1] = p2;
            }
        }
        __syncthreads();
        if (tid == 0) arrive(flags, 1);
    } else if (bid < 404) {
        // ---- comp: finalize LN stats, bvec in LDS, comp matvec (4 e's)
        wait_flag(flags, 1, 112, tid);

        if (tid < BBATCH * KEXP) {
            const int b = tid / KEXP;
            const int k = tid % KEXP;
            float s1 = 0.f, s2 = 0.f;
#pragma unroll
            for (int c = 0; c < 16; ++c) {
                s1 += ws[WS_PSTAT + ((b * KEXP + k) * 16 + c) * 2 + 0];
                s2 += ws[WS_PSTAT + ((b * KEXP + k) * 16 + c) * 2 + 1];
            }
            const float mu = s1 * (1.f / (float)DDIM);
            const float var = s2 * (1.f / (float)DDIM) - mu * mu;
            const float rs = rsqrtf(var + LN_EPS_C);
            const float w = ws[WS_W + b * 8 + k];
            sA[b * KEXP + k] = w * rs;          // alpha
            sA[28 + b * KEXP + k] = w * rs * mu; // alpha*mu
        }
        __syncthreads();
        if (tid < BBATCH) {
            float c = 0.f;
#pragma unroll
            for (int k = 0; k < KEXP; ++k) c += sA[28 + tid * KEXP + k];
            sA[56 + tid] = c;                    // Cb
            sA[60 + tid] = ws[WS_W + tid * 8 + 7]; // wsum
        }
        __syncthreads();

        {
            const float4 g4 = ((const float4*)ln_g)[tid];
            const float4 b4 = ((const float4*)ln_b)[tid];
            const float4* s4p = (const float4*)(ws + WS_S);
#pragma unroll
            for (int b = 0; b < BBATCH; ++b) {
                float4 s = make_float4(0.f, 0.f, 0.f, 0.f);
#pragma unroll
                for (int k = 0; k < KEXP; ++k) {
                    const float a = sA[b * KEXP + k];
                    float4 v = s4p[(size_t)(b * KEXP + k) * 256 + tid];
                    s.x = fmaf(a, v.x, s.x);
                    s.y = fmaf(a, v.y, s.y);
                    s.z = fmaf(a, v.z, s.z);
                    s.w = fmaf(a, v.w, s.w);
                }
                const float C = sA[56 + b], wsum = sA[60 + b];
                float4 o;
                o.x = g4.x * (s.x - C) + b4.x * wsum;
                o.y = g4.y * (s.y - C) + b4.y * wsum;
                o.z = g4.z * (s.z - C) + b4.z * wsum;
                o.w = g4.w * (s.w - C) + b4.w * wsum;
                sB[b * 256 + tid] = o;
            }
        }
        __syncthreads();

        const int e = (bid - 148) * 4 + wv;
        const float4* cw4 = (const float4*)(comp_w + (size_t)e * DDIM);
        float acc[BBATCH] = {0.f, 0.f, 0.f, 0.f};
#pragma unroll
        for (int j = 0; j < 4; ++j) {
            float4 c = cw4[j * 64 + lane];
#pragma unroll
            for (int b = 0; b < BBATCH; ++b) acc[b] += dot4(c, sB[b * 256 + j * 64 + lane]);
        }
#pragma unroll
        for (int b = 0; b < BBATCH; ++b)
#pragma unroll
            for (int off = 32; off > 0; off >>= 1)
                acc[b] += __shfl_xor(acc[b], off, 64);
        if (lane == 0) {
            const float cb = comp_b[e];
#pragma unroll
            for (int b = 0; b < BBATCH; ++b)
                out[b * DDIM + e] = acc[b] + cb;
        }
        __syncthreads();
    }
    // bid 404..547: straight to gate stealing

    // ======================= gate steal phase =======================
    // register-stage gate_w fragments (28 float4/lane) once per block
    const float4* gw4 = (const float4*)gate_w;
    float4 gw[KEXP][4];
#pragma unroll
    for (int k = 0; k < KEXP; ++k)
#pragma unroll
        for (int j = 0; j < 4; ++j)
            gw[k][j] = gw4[k * 256 + j * 64 + lane];
    float gb[KEXP];
#pragma unroll
    for (int k = 0; k < KEXP; ++k) gb[k] = gate_b[k];

    for (;;) {
        if (tid == 0)
            sChunk = __hip_atomic_fetch_add(&flags[2], 1, __ATOMIC_RELAXED, __HIP_MEMORY_SCOPE_AGENT);
        __syncthreads();
        const int c = sChunk;
        __syncthreads();
        if (c >= NCHUNK) break;
        const int row0 = c * 16 + wv * 4;
#pragma unroll
        for (int r = 0; r < 4; ++r) {
            const int row = row0 + r;
            const float4* h4 = (const float4*)(h + (size_t)row * DDIM);
            float acc[KEXP];
#pragma unroll
            for (int k = 0; k < KEXP; ++k) acc[k] = 0.f;
#pragma unroll
            for (int j = 0; j < 4; ++j) {
                float4 hv = h4[j * 64 + lane];
#pragma unroll
                for (int k = 0; k < KEXP; ++k) {
                    acc[k] = fmaf(hv.x, gw[k][j].x, acc[k]);
                    acc[k] = fmaf(hv.y, gw[k][j].y, acc[k]);
                    acc[k] = fmaf(hv.z, gw[k][j].z, acc[k]);
                    acc[k] = fmaf(hv.w, gw[k][j].w, acc[k]);
                }
            }
#pragma unroll
            for (int k = 0; k < KEXP; ++k) {
#pragma unroll
                for (int off = 32; off > 0; off >>= 1)
                    acc[k] += __shfl_xor(acc[k], off, 64);
            }
            float m = -1e30f;
#pragma unroll
            for (int k = 0; k < KEXP; ++k) { acc[k] += gb[k]; m = fmaxf(m, acc[k]); }
            float e[KEXP];
            float s = 0.f;
#pragma unroll
            for (int k = 0; k < KEXP; ++k) { e[k] = expf(acc[k] - m); s += e[k]; }
            const float inv = 1.f / s;
            if (lane == 0) {
#pragma unroll
                for (int k = 0; k < KEXP; ++k) G[row * KEXP + k] = e[k] * inv;
            }
        }
    }
}

extern "C" void kernel_launch(void* const* d_in, const int* in_sizes, int n_in,
                              void* d_out, int out_size, void* d_ws, size_t ws_size,
                              hipStream_t stream) {
    const float* h      = (const float*)d_in[0];
    const float* gate_w = (const float*)d_in[1];
    const float* gate_b = (const float*)d_in[2];
    const float* U_w    = (const float*)d_in[3];
    const float* V      = (const float*)d_in[4];
    const float* ln_g   = (const float*)d_in[5];
    const float* ln_b   = (const float*)d_in[6];
    const float* comp_w = (const float*)d_in[7];
    const float* comp_b = (const float*)d_in[8];

    float* out = (float*)d_out;                 // b: 4*1024 floats
    float* G   = out + BBATCH * DDIM;           // G: 4*2048*7 floats
    float* ws  = (float*)d_ws;

    // zero the sync flags (first 256 B of ws) every call — deterministic
    hipMemsetAsync(d_ws, 0, 256, stream);
    k_mega<<<548, 256, 0, stream>>>(h, gate_w, gate_b, U_w, V, ln_g, ln_b,
                                    comp_w, comp_b, G, out, ws);
}

// Round 6
// 146.232 us; speedup vs baseline: 1.0655x; 1.0655x over previous
//
#include <hip/hip_runtime.h>
#include <hip/hip_cooperative_groups.h>
#include <math.h>

namespace cg = cooperative_groups;

#define KEXP 7
#define DDIM 1024
#define RDIM 128
#define TSEQ 2048
#define BBATCH 4
#define TAU_C 1.2f
#define EPS_C 1e-9f
#define LN_EPS_C 1e-5f

// ws float offsets
#define WS_S     0                    // s[b][k][1024]      : 28672 floats
#define WS_BASIS 28672                // basis[b][128]      : 512
#define WS_W     (WS_BASIS + 512)     // w[b][8]            : 32
#define WS_PSTAT (WS_W + 32)          // pstat[b][k][16][2] : 896

__device__ __forceinline__ float dot4(float4 a, float4 b) {
    return fmaf(a.x, b.x, fmaf(a.y, b.y, fmaf(a.z, b.z, a.w * b.w)));
}

// ---------------- shared device helpers (roles) ----------------

// basis role: one of 32 blocks; basis[b][r] = h_last . U_w[r], 16 r's per block
__device__ __forceinline__ void role_basis(int idx, const float* __restrict__ h,
                                           const float* __restrict__ U_w,
                                           float* __restrict__ ws, int lane, int wv) {
    const int b = idx >> 3;
    const int chunk = idx & 7;
    const float4* h4 = (const float4*)(h + ((size_t)b * TSEQ + (TSEQ - 1)) * DDIM);
    float4 hf[4];
#pragma unroll
    for (int j = 0; j < 4; ++j) hf[j] = h4[j * 64 + lane];
    const int r0 = chunk * 16 + wv * 4;
    float part[4];
#pragma unroll
    for (int rr = 0; rr < 4; ++rr) {
        const float4* u4 = (const float4*)(U_w + (size_t)(r0 + rr) * DDIM);
        float a = 0.f;
#pragma unroll
        for (int j = 0; j < 4; ++j) a += dot4(hf[j], u4[j * 64 + lane]);
        part[rr] = a;
    }
#pragma unroll
    for (int off = 32; off > 0; off >>= 1)
#pragma unroll
        for (int rr = 0; rr < 4; ++rr)
            part[rr] += __shfl_xor(part[rr], off, 64);
    if (lane == 0) {
#pragma unroll
        for (int rr = 0; rr < 4; ++rr)
            ws[WS_BASIS + b * RDIM + r0 + rr] = part[rr];
    }
}

// weights role: leftover weights for batch b (sA must be >=8 floats of LDS)
__device__ __forceinline__ void role_weights(int b, const float* __restrict__ h,
                                             const float* __restrict__ gate_w,
                                             const float* __restrict__ gate_b,
                                             float* __restrict__ ws, float* sA,
                                             int tid, int lane, int wv) {
    const float4* h4 = (const float4*)(h + ((size_t)b * TSEQ + (TSEQ - 1)) * DDIM);
    for (int e = wv; e < KEXP; e += 4) {
        const float4* gw4 = (const float4*)(gate_w + (size_t)e * DDIM);
        float a = 0.f;
#pragma unroll
        for (int j = 0; j < 4; ++j) a += dot4(h4[j * 64 + lane], gw4[j * 64 + lane]);
#pragma unroll
        for (int off = 32; off > 0; off >>= 1) a += __shfl_xor(a, off, 64);
        if (lane == 0) sA[e] = a + gate_b[e];
    }
    __syncthreads();
    if (tid == 0) {
        float l0[KEXP], m0 = -1e30f;
#pragma unroll
        for (int j = 0; j < KEXP; ++j) { l0[j] = sA[j]; m0 = fmaxf(m0, l0[j]); }
        float es0 = 0.f, g[KEXP];
#pragma unroll
        for (int j = 0; j < KEXP; ++j) { g[j] = expf(l0[j] - m0); es0 += g[j]; }
        const float inv0 = 1.f / es0;
#pragma unroll
        for (int j = 0; j < KEXP; ++j) g[j] *= inv0;
        int i1 = 0;
        for (int j = 1; j < KEXP; ++j) if (g[j] > g[i1]) i1 = j;
        int i2 = -1;
        for (int j = 0; j < KEXP; ++j)
            if (j != i1 && (i2 < 0 || g[j] > g[i2])) i2 = j;
        int i3 = -1;
        for (int j = 0; j < KEXP; ++j)
            if (j != i1 && j != i2 && (i3 < 0 || g[j] > g[i3])) i3 = j;
        int i4 = -1;
        for (int j = 0; j < KEXP; ++j)
            if (j != i1 && j != i2 && j != i3 && (i4 < 0 || g[j] > g[i4])) i4 = j;
        float s = fmaxf(g[i3] + g[i4], EPS_C);
        float p[KEXP];
#pragma unroll
        for (int j = 0; j < KEXP; ++j) p[j] = 0.f;
        p[i3] = g[i3] / s;
        p[i4] = g[i4] / s;
        float l[KEXP], m = -1e30f;
#pragma unroll
        for (int j = 0; j < KEXP; ++j) {
            l[j] = logf(fmaxf(p[j], EPS_C)) * (1.f / TAU_C);
            m = fmaxf(m, l[j]);
        }
        float es = 0.f, w[KEXP];
#pragma unroll
        for (int j = 0; j < KEXP; ++j) { w[j] = expf(l[j] - m); es += w[j]; }
        const float inv = 1.f / es;
        float wsum = 0.f;
#pragma unroll
        for (int j = 0; j < KEXP; ++j) { w[j] *= inv; wsum += w[j]; ws[WS_W + b * 8 + j] = w[j]; }
        ws[WS_W + b * 8 + 7] = wsum;
    }
}

// one 16-row gate chunk: logits + softmax -> G rows [c*16, c*16+16)
__device__ __forceinline__ void gate_chunk(int c, const float* __restrict__ h,
                                           const float* __restrict__ gate_w,
                                           const float* __restrict__ gate_b,
                                           float* __restrict__ G,
                                           int lane, int wv) {
    const float4* gw4 = (const float4*)gate_w;
    float4 gw[KEXP][4];
#pragma unroll
    for (int k = 0; k < KEXP; ++k)
#pragma unroll
        for (int j = 0; j < 4; ++j)
            gw[k][j] = gw4[k * 256 + j * 64 + lane];
    float gb[KEXP];
#pragma unroll
    for (int k = 0; k < KEXP; ++k) gb[k] = gate_b[k];

    const int row0 = c * 16 + wv * 4;
#pragma unroll
    for (int r = 0; r < 4; ++r) {
        const int row = row0 + r;
        const float4* h4 = (const float4*)(h + (size_t)row * DDIM);
        float acc[KEXP];
#pragma unroll
        for (int k = 0; k < KEXP; ++k) acc[k] = 0.f;
#pragma unroll
        for (int j = 0; j < 4; ++j) {
            float4 hv = h4[j * 64 + lane];
#pragma unroll
            for (int k = 0; k < KEXP; ++k) {
                acc[k] = fmaf(hv.x, gw[k][j].x, acc[k]);
                acc[k] = fmaf(hv.y, gw[k][j].y, acc[k]);
                acc[k] = fmaf(hv.z, gw[k][j].z, acc[k]);
                acc[k] = fmaf(hv.w, gw[k][j].w, acc[k]);
            }
        }
#pragma unroll
        for (int k = 0; k < KEXP; ++k) {
#pragma unroll
            for (int off = 32; off > 0; off >>= 1)
                acc[k] += __shfl_xor(acc[k], off, 64);
        }
        float m = -1e30f;
#pragma unroll
        for (int k = 0; k < KEXP; ++k) { acc[k] += gb[k]; m = fmaxf(m, acc[k]); }
        float e[KEXP];
        float s = 0.f;
#pragma unroll
        for (int k = 0; k < KEXP; ++k) { e[k] = expf(acc[k] - m); s += e[k]; }
        const float inv = 1.f / s;
        if (lane == 0) {
#pragma unroll
            for (int k = 0; k < KEXP; ++k) G[row * KEXP + k] = e[k] * inv;
        }
    }
}

// sv role: s[b][k][64-d chunk] for all b, + partial LN stats. Needs sA[512], sB[1024].
__device__ __forceinline__ void role_sv(int idx, const float* __restrict__ V,
                                        float* __restrict__ ws, float* sA, float4* sB,
                                        int tid) {
    const int k = idx >> 4;
    const int chunk = idx & 15;
    const int col = tid & 15;
    const int rc = tid >> 4;

    sA[tid] = ws[WS_BASIS + tid];
    sA[tid + 256] = ws[WS_BASIS + tid + 256];
    __syncthreads();

    const float4* V4 = (const float4*)(V + (size_t)k * RDIM * DDIM);
    float4 acc[BBATCH];
#pragma unroll
    for (int b = 0; b < BBATCH; ++b) acc[b] = make_float4(0.f, 0.f, 0.f, 0.f);
#pragma unroll
    for (int rr = 0; rr < 8; ++rr) {
        const int r = rc * 8 + rr;
        float4 v = V4[(size_t)r * 256 + chunk * 16 + col];
#pragma unroll
        for (int b = 0; b < BBATCH; ++b) {
            const float br = sA[b * RDIM + r];
            acc[b].x = fmaf(br, v.x, acc[b].x);
            acc[b].y = fmaf(br, v.y, acc[b].y);
            acc[b].z = fmaf(br, v.z, acc[b].z);
            acc[b].w = fmaf(br, v.w, acc[b].w);
        }
    }
#pragma unroll
    for (int b = 0; b < BBATCH; ++b) sB[(rc * 4 + b) * 16 + col] = acc[b];
    __syncthreads();

    if (tid < 64) {
        const int b = tid >> 4;
        const int c = tid & 15;
        float4 s4 = make_float4(0.f, 0.f, 0.f, 0.f);
#pragma unroll
        for (int q = 0; q < 16; ++q) {
            float4 p = sB[(q * 4 + b) * 16 + c];
            s4.x += p.x; s4.y += p.y; s4.z += p.z; s4.w += p.w;
        }
        ((float4*)(ws + WS_S))[(size_t)(b * KEXP + k) * 256 + chunk * 16 + c] = s4;
        float p1 = s4.x + s4.y + s4.z + s4.w;
        float p2 = dot4(s4, s4);
#pragma unroll
        for (int off = 8; off > 0; off >>= 1) {
            p1 += __shfl_xor(p1, off, 64);
            p2 += __shfl_xor(p2, off, 64);
        }
        if (c == 0) {
            ws[WS_PSTAT + ((b * KEXP + k) * 16 + chunk) * 2 + 0] = p1;
            ws[WS_PSTAT + ((b * KEXP + k) * 16 + chunk) * 2 + 1] = p2;
        }
    }
}

// comp role: finalize LN stats, bvec in LDS, comp matvec for 4 e's.
__device__ __forceinline__ void role_comp(int cb_idx, const float* __restrict__ ws,
                                          const float* __restrict__ ln_g,
                                          const float* __restrict__ ln_b,
                                          const float* __restrict__ comp_w,
                                          const float* __restrict__ comp_b,
                                          float* __restrict__ out,
                                          float* sA, float4* sB,
                                          int tid, int lane, int wv) {
    if (tid < BBATCH * KEXP) {
        const int b = tid / KEXP;
        const int k = tid % KEXP;
        float s1 = 0.f, s2 = 0.f;
#pragma unroll
        for (int c = 0; c < 16; ++c) {
            s1 += ws[WS_PSTAT + ((b * KEXP + k) * 16 + c) * 2 + 0];
            s2 += ws[WS_PSTAT + ((b * KEXP + k) * 16 + c) * 2 + 1];
        }
        const float mu = s1 * (1.f / (float)DDIM);
        const float var = s2 * (1.f / (float)DDIM) - mu * mu;
        const float rs = rsqrtf(var + LN_EPS_C);
        const float w = ws[WS_W + b * 8 + k];
        sA[b * KEXP + k] = w * rs;            // alpha
        sA[28 + b * KEXP + k] = w * rs * mu;  // alpha*mu
    }
    __syncthreads();
    if (tid < BBATCH) {
        float c = 0.f;
#pragma unroll
        for (int k = 0; k < KEXP; ++k) c += sA[28 + tid * KEXP + k];
        sA[56 + tid] = c;                      // Cb
        sA[60 + tid] = ws[WS_W + tid * 8 + 7]; // wsum
    }
    __syncthreads();

    {
        const float4 g4 = ((const float4*)ln_g)[tid];
        const float4 b4 = ((const float4*)ln_b)[tid];
        const float4* s4p = (const float4*)(ws + WS_S);
#pragma unroll
        for (int b = 0; b < BBATCH; ++b) {
            float4 s = make_float4(0.f, 0.f, 0.f, 0.f);
#pragma unroll
            for (int k = 0; k < KEXP; ++k) {
                const float a = sA[b * KEXP + k];
                float4 v = s4p[(size_t)(b * KEXP + k) * 256 + tid];
                s.x = fmaf(a, v.x, s.x);
                s.y = fmaf(a, v.y, s.y);
                s.z = fmaf(a, v.z, s.z);
                s.w = fmaf(a, v.w, s.w);
            }
            const float C = sA[56 + b], wsum = sA[60 + b];
            float4 o;
            o.x = g4.x * (s.x - C) + b4.x * wsum;
            o.y = g4.y * (s.y - C) + b4.y * wsum;
            o.z = g4.z * (s.z - C) + b4.z * wsum;
            o.w = g4.w * (s.w - C) + b4.w * wsum;
            sB[b * 256 + tid] = o;
        }
    }
    __syncthreads();

    const int e = cb_idx * 4 + wv;
    const float4* cw4 = (const float4*)(comp_w + (size_t)e * DDIM);
    float acc[BBATCH] = {0.f, 0.f, 0.f, 0.f};
#pragma unroll
    for (int j = 0; j < 4; ++j) {
        float4 c = cw4[j * 64 + lane];
#pragma unroll
        for (int b = 0; b < BBATCH; ++b) acc[b] += dot4(c, sB[b * 256 + j * 64 + lane]);
    }
#pragma unroll
    for (int b = 0; b < BBATCH; ++b)
#pragma unroll
        for (int off = 32; off > 0; off >>= 1)
            acc[b] += __shfl_xor(acc[b], off, 64);
    if (lane == 0) {
        const float cb = comp_b[e];
#pragma unroll
        for (int b = 0; b < BBATCH; ++b)
            out[b * DDIM + e] = acc[b] + cb;
    }
}

// ===================== cooperative single-kernel path =====================
__global__ __launch_bounds__(256, 2) void k_mega(const float* __restrict__ h,
                                                 const float* __restrict__ gate_w,
                                                 const float* __restrict__ gate_b,
                                                 const float* __restrict__ U_w,
                                                 const float* __restrict__ V,
                                                 const float* __restrict__ ln_g,
                                                 const float* __restrict__ ln_b,
                                                 const float* __restrict__ comp_w,
                                                 const float* __restrict__ comp_b,
                                                 float* __restrict__ G,
                                                 float* __restrict__ out,
                                                 float* __restrict__ ws) {
    cg::grid_group gg = cg::this_grid();
    const int bid = blockIdx.x;
    const int tid = threadIdx.x;
    const int lane = tid & 63;
    const int wv = tid >> 6;

    __shared__ float sA[512];
    __shared__ float4 sB[1024];

    // phase 0: basis (0..31), weights (32..35), gate chunks 0..475 (36..511)
    if (bid < 32)       role_basis(bid, h, U_w, ws, lane, wv);
    else if (bid < 36)  role_weights(bid - 32, h, gate_w, gate_b, ws, sA, tid, lane, wv);
    else                gate_chunk(bid - 36, h, gate_w, gate_b, G, lane, wv);

    gg.sync();

    // phase 1: gate chunks 476..511 (0..35), sv (36..147)
    if (bid < 36)       gate_chunk(bid + 476, h, gate_w, gate_b, G, lane, wv);
    else if (bid < 148) role_sv(bid - 36, V, ws, sA, sB, tid);

    gg.sync();

    // phase 2: comp (0..255)
    if (bid < 256)
        role_comp(bid, ws, ln_g, ln_b, comp_w, comp_b, out, sA, sB, tid, lane, wv);
}

// ===================== fallback 3-kernel path =====================
__global__ __launch_bounds__(256) void k_prep(const float* __restrict__ h,
                                              const float* __restrict__ gate_w,
                                              const float* __restrict__ gate_b,
                                              const float* __restrict__ U_w,
                                              float* __restrict__ ws) {
    __shared__ float sA[8];
    const int tid = threadIdx.x;
    const int lane = tid & 63;
    const int wv = tid >> 6;
    if (blockIdx.x < 32) role_basis(blockIdx.x, h, U_w, ws, lane, wv);
    else                 role_weights(blockIdx.x - 32, h, gate_w, gate_b, ws, sA, tid, lane, wv);
}

// 624 blocks: 0..111 sv, 112..623 gate chunks 0..511 (sv and gate are independent)
__global__ __launch_bounds__(256) void k_main(const float* __restrict__ h,
                                              const float* __restrict__ gate_w,
                                              const float* __restrict__ gate_b,
                                              const float* __restrict__ V,
                                              float* __restrict__ G,
                                              float* __restrict__ ws) {
    __shared__ float sA[512];
    __shared__ float4 sB[1024];
    const int tid = threadIdx.x;
    const int lane = tid & 63;
    const int wv = tid >> 6;
    if (blockIdx.x < 112) role_sv(blockIdx.x, V, ws, sA, sB, tid);
    else                  gate_chunk(blockIdx.x - 112, h, gate_w, gate_b, G, lane, wv);
}

__global__ __launch_bounds__(256) void k_comp2(const float* __restrict__ ws,
                                               const float* __restrict__ ln_g,
                                               const float* __restrict__ ln_b,
                                               const float* __restrict__ comp_w,
                                               const float* __restrict__ comp_b,
                                               float* __restrict__ out) {
    __shared__ float sA[512];
    __shared__ float4 sB[1024];
    const int tid = threadIdx.x;
    const int lane = tid & 63;
    const int wv = tid >> 6;
    role_comp(blockIdx.x, ws, ln_g, ln_b, comp_w, comp_b, out, sA, sB, tid, lane, wv);
}

extern "C" void kernel_launch(void* const* d_in, const int* in_sizes, int n_in,
                              void* d_out, int out_size, void* d_ws, size_t ws_size,
                              hipStream_t stream) {
    const float* h      = (const float*)d_in[0];
    const float* gate_w = (const float*)d_in[1];
    const float* gate_b = (const float*)d_in[2];
    const float* U_w    = (const float*)d_in[3];
    const float* V      = (const float*)d_in[4];
    const float* ln_g   = (const float*)d_in[5];
    const float* ln_b   = (const float*)d_in[6];
    const float* comp_w = (const float*)d_in[7];
    const float* comp_b = (const float*)d_in[8];

    float* out = (float*)d_out;                 // b: 4*1024 floats
    float* G   = out + BBATCH * DDIM;           // G: 4*2048*7 floats
    float* ws  = (float*)d_ws;

    void* kargs[] = {(void*)&h, (void*)&gate_w, (void*)&gate_b, (void*)&U_w,
                     (void*)&V, (void*)&ln_g, (void*)&ln_b, (void*)&comp_w,
                     (void*)&comp_b, (void*)&G, (void*)&out, (void*)&ws};
    hipError_t err = hipLaunchCooperativeKernel((void*)k_mega, dim3(512), dim3(256),
                                                kargs, 0, stream);
    if (err != hipSuccess) {
        // deterministic fallback: 3-kernel pipeline with sv hidden under gate
        k_prep<<<36, 256, 0, stream>>>(h, gate_w, gate_b, U_w, ws);
        k_main<<<624, 256, 0, stream>>>(h, gate_w, gate_b, V, G, ws);
        k_comp2<<<256, 256, 0, stream>>>(ws, ln_g, ln_b, comp_w, comp_b, out);
    }
}

// Round 7
// 78.233 us; speedup vs baseline: 1.9916x; 1.8692x over previous
//
#include <hip/hip_runtime.h>
#include <math.h>

#define KEXP 7
#define DDIM 1024
#define RDIM 128
#define TSEQ 2048
#define BBATCH 4
#define TAU_C 1.2f
#define EPS_C 1e-9f
#define LN_EPS_C 1e-5f

// ---- ws layout ----
// int flags[148], flag i at int offset i*32 (128-B spacing, write-once each)
// then float data:
#define FLAG_INTS (148 * 32)              // 4736 ints = 18944 B (memset region)
#define WS_S     FLAG_INTS                // s[b][k][1024]      : 28672 floats
#define WS_BASIS (WS_S + 28672)           // basis[b][128]      : 512
#define WS_W     (WS_BASIS + 512)         // w[b][8]            : 32
#define WS_PSTAT (WS_W + 32)              // pstat[b][k][16][2] : 896

// flag indices: 0..31 basis, 32..35 weights, 36..147 sv
#define FLG_BASIS 0
#define FLG_WGT   32
#define FLG_SV    36

__device__ __forceinline__ float dot4(float4 a, float4 b) {
    return fmaf(a.x, b.x, fmaf(a.y, b.y, fmaf(a.z, b.z, a.w * b.w)));
}

// tid 0 only, after __syncthreads(). Write-once flag on its own cache line.
__device__ __forceinline__ void publish(int* flags, int idx) {
    __threadfence();
    __hip_atomic_store(&flags[idx * 32], 1, __ATOMIC_RELEASE, __HIP_MEMORY_SCOPE_AGENT);
}

// threads 0..count-1 poll one flag each (acquire); then block barrier.
__device__ __forceinline__ void wait_flags(int* flags, int base, int count, int tid) {
    if (tid < count) {
        while (__hip_atomic_load(&flags[(base + tid) * 32], __ATOMIC_ACQUIRE,
                                 __HIP_MEMORY_SCOPE_AGENT) == 0)
            __builtin_amdgcn_s_sleep(4);
    }
    __syncthreads();
}

// ---------------- roles ----------------

// basis: basis[b][r] = h_last . U_w[r], 16 r's per block (idx 0..31)
__device__ __forceinline__ void role_basis(int idx, const float* __restrict__ h,
                                           const float* __restrict__ U_w,
                                           float* __restrict__ ws, int lane, int wv) {
    const int b = idx >> 3;
    const int chunk = idx & 7;
    const float4* h4 = (const float4*)(h + ((size_t)b * TSEQ + (TSEQ - 1)) * DDIM);
    float4 hf[4];
#pragma unroll
    for (int j = 0; j < 4; ++j) hf[j] = h4[j * 64 + lane];
    const int r0 = chunk * 16 + wv * 4;
    float part[4];
#pragma unroll
    for (int rr = 0; rr < 4; ++rr) {
        const float4* u4 = (const float4*)(U_w + (size_t)(r0 + rr) * DDIM);
        float a = 0.f;
#pragma unroll
        for (int j = 0; j < 4; ++j) a += dot4(hf[j], u4[j * 64 + lane]);
        part[rr] = a;
    }
#pragma unroll
    for (int off = 32; off > 0; off >>= 1)
#pragma unroll
        for (int rr = 0; rr < 4; ++rr)
            part[rr] += __shfl_xor(part[rr], off, 64);
    if (lane == 0) {
#pragma unroll
        for (int rr = 0; rr < 4; ++rr)
            ws[WS_BASIS + b * RDIM + r0 + rr] = part[rr];
    }
}

// weights: leftover weights for batch b (sA >= 8 floats)
__device__ __forceinline__ void role_weights(int b, const float* __restrict__ h,
                                             const float* __restrict__ gate_w,
                                             const float* __restrict__ gate_b,
                                             float* __restrict__ ws, float* sA,
                                             int tid, int lane, int wv) {
    const float4* h4 = (const float4*)(h + ((size_t)b * TSEQ + (TSEQ - 1)) * DDIM);
    for (int e = wv; e < KEXP; e += 4) {
        const float4* gw4 = (const float4*)(gate_w + (size_t)e * DDIM);
        float a = 0.f;
#pragma unroll
        for (int j = 0; j < 4; ++j) a += dot4(h4[j * 64 + lane], gw4[j * 64 + lane]);
#pragma unroll
        for (int off = 32; off > 0; off >>= 1) a += __shfl_xor(a, off, 64);
        if (lane == 0) sA[e] = a + gate_b[e];
    }
    __syncthreads();
    if (tid == 0) {
        float l0[KEXP], m0 = -1e30f;
#pragma unroll
        for (int j = 0; j < KEXP; ++j) { l0[j] = sA[j]; m0 = fmaxf(m0, l0[j]); }
        float es0 = 0.f, g[KEXP];
#pragma unroll
        for (int j = 0; j < KEXP; ++j) { g[j] = expf(l0[j] - m0); es0 += g[j]; }
        const float inv0 = 1.f / es0;
#pragma unroll
        for (int j = 0; j < KEXP; ++j) g[j] *= inv0;
        int i1 = 0;
        for (int j = 1; j < KEXP; ++j) if (g[j] > g[i1]) i1 = j;
        int i2 = -1;
        for (int j = 0; j < KEXP; ++j)
            if (j != i1 && (i2 < 0 || g[j] > g[i2])) i2 = j;
        int i3 = -1;
        for (int j = 0; j < KEXP; ++j)
            if (j != i1 && j != i2 && (i3 < 0 || g[j] > g[i3])) i3 = j;
        int i4 = -1;
        for (int j = 0; j < KEXP; ++j)
            if (j != i1 && j != i2 && j != i3 && (i4 < 0 || g[j] > g[i4])) i4 = j;
        float s = fmaxf(g[i3] + g[i4], EPS_C);
        float p[KEXP];
#pragma unroll
        for (int j = 0; j < KEXP; ++j) p[j] = 0.f;
        p[i3] = g[i3] / s;
        p[i4] = g[i4] / s;
        float l[KEXP], m = -1e30f;
#pragma unroll
        for (int j = 0; j < KEXP; ++j) {
            l[j] = logf(fmaxf(p[j], EPS_C)) * (1.f / TAU_C);
            m = fmaxf(m, l[j]);
        }
        float es = 0.f, w[KEXP];
#pragma unroll
        for (int j = 0; j < KEXP; ++j) { w[j] = expf(l[j] - m); es += w[j]; }
        const float inv = 1.f / es;
        float wsum = 0.f;
#pragma unroll
        for (int j = 0; j < KEXP; ++j) { w[j] *= inv; wsum += w[j]; ws[WS_W + b * 8 + j] = w[j]; }
        ws[WS_W + b * 8 + 7] = wsum;
    }
}

// one 16-row gate chunk: logits + softmax -> G rows [c*16, c*16+16)
// __noinline__: isolates the 112-VGPR gw staging from the other roles' regalloc.
__device__ __noinline__ void gate_chunk(int c, const float* __restrict__ h,
                                        const float* __restrict__ gate_w,
                                        const float* __restrict__ gate_b,
                                        float* __restrict__ G,
                                        int lane, int wv) {
    const float4* gw4 = (const float4*)gate_w;
    float4 gw[KEXP][4];
#pragma unroll
    for (int k = 0; k < KEXP; ++k)
#pragma unroll
        for (int j = 0; j < 4; ++j)
            gw[k][j] = gw4[k * 256 + j * 64 + lane];
    float gb[KEXP];
#pragma unroll
    for (int k = 0; k < KEXP; ++k) gb[k] = gate_b[k];

    const int row0 = c * 16 + wv * 4;
#pragma unroll
    for (int r = 0; r < 4; ++r) {
        const int row = row0 + r;
        const float4* h4 = (const float4*)(h + (size_t)row * DDIM);
        float acc[KEXP];
#pragma unroll
        for (int k = 0; k < KEXP; ++k) acc[k] = 0.f;
#pragma unroll
        for (int j = 0; j < 4; ++j) {
            float4 hv = h4[j * 64 + lane];
#pragma unroll
            for (int k = 0; k < KEXP; ++k) {
                acc[k] = fmaf(hv.x, gw[k][j].x, acc[k]);
                acc[k] = fmaf(hv.y, gw[k][j].y, acc[k]);
                acc[k] = fmaf(hv.z, gw[k][j].z, acc[k]);
                acc[k] = fmaf(hv.w, gw[k][j].w, acc[k]);
            }
        }
#pragma unroll
        for (int k = 0; k < KEXP; ++k) {
#pragma unroll
            for (int off = 32; off > 0; off >>= 1)
                acc[k] += __shfl_xor(acc[k], off, 64);
        }
        float m = -1e30f;
#pragma unroll
        for (int k = 0; k < KEXP; ++k) { acc[k] += gb[k]; m = fmaxf(m, acc[k]); }
        float e[KEXP];
        float s = 0.f;
#pragma unroll
        for (int k = 0; k < KEXP; ++k) { e[k] = expf(acc[k] - m); s += e[k]; }
        const float inv = 1.f / s;
        if (lane == 0) {
#pragma unroll
            for (int k = 0; k < KEXP; ++k) G[row * KEXP + k] = e[k] * inv;
        }
    }
}

// sv: s[b][k][64-d chunk] for all b, + partial LN stats. Needs sA[512], sB[1024].
__device__ __noinline__ void role_sv(int idx, const float* __restrict__ V,
                                     float* __restrict__ ws, float* sA, float4* sB,
                                     int tid) {
    const int k = idx >> 4;
    const int chunk = idx & 15;
    const int col = tid & 15;
    const int rc = tid >> 4;

    sA[tid] = ws[WS_BASIS + tid];
    sA[tid + 256] = ws[WS_BASIS + tid + 256];
    __syncthreads();

    const float4* V4 = (const float4*)(V + (size_t)k * RDIM * DDIM);
    float4 acc[BBATCH];
#pragma unroll
    for (int b = 0; b < BBATCH; ++b) acc[b] = make_float4(0.f, 0.f, 0.f, 0.f);
#pragma unroll
    for (int rr = 0; rr < 8; ++rr) {
        const int r = rc * 8 + rr;
        float4 v = V4[(size_t)r * 256 + chunk * 16 + col];
#pragma unroll
        for (int b = 0; b < BBATCH; ++b) {
            const float br = sA[b * RDIM + r];
            acc[b].x = fmaf(br, v.x, acc[b].x);
            acc[b].y = fmaf(br, v.y, acc[b].y);
            acc[b].z = fmaf(br, v.z, acc[b].z);
            acc[b].w = fmaf(br, v.w, acc[b].w);
        }
    }
#pragma unroll
    for (int b = 0; b < BBATCH; ++b) sB[(rc * 4 + b) * 16 + col] = acc[b];
    __syncthreads();

    if (tid < 64) {
        const int b = tid >> 4;
        const int c = tid & 15;
        float4 s4 = make_float4(0.f, 0.f, 0.f, 0.f);
#pragma unroll
        for (int q = 0; q < 16; ++q) {
            float4 p = sB[(q * 4 + b) * 16 + c];
            s4.x += p.x; s4.y += p.y; s4.z += p.z; s4.w += p.w;
        }
        ((float4*)(ws + WS_S))[(size_t)(b * KEXP + k) * 256 + chunk * 16 + c] = s4;
        float p1 = s4.x + s4.y + s4.z + s4.w;
        float p2 = dot4(s4, s4);
#pragma unroll
        for (int off = 8; off > 0; off >>= 1) {
            p1 += __shfl_xor(p1, off, 64);
            p2 += __shfl_xor(p2, off, 64);
        }
        if (c == 0) {
            ws[WS_PSTAT + ((b * KEXP + k) * 16 + chunk) * 2 + 0] = p1;
            ws[WS_PSTAT + ((b * KEXP + k) * 16 + chunk) * 2 + 1] = p2;
        }
    }
}

// comp: finalize LN stats, bvec in LDS, comp matvec for e = cb_idx*4 + wv.
__device__ __noinline__ void role_comp(int cb_idx, const float* __restrict__ ws,
                                       const float* __restrict__ ln_g,
                                       const float* __restrict__ ln_b,
                                       const float* __restrict__ comp_w,
                                       const float* __restrict__ comp_b,
                                       float* __restrict__ out,
                                       float* sA, float4* sB,
                                       int tid, int lane, int wv) {
    if (tid < BBATCH * KEXP) {
        const int b = tid / KEXP;
        const int k = tid % KEXP;
        float s1 = 0.f, s2 = 0.f;
#pragma unroll
        for (int c = 0; c < 16; ++c) {
            s1 += ws[WS_PSTAT + ((b * KEXP + k) * 16 + c) * 2 + 0];
            s2 += ws[WS_PSTAT + ((b * KEXP + k) * 16 + c) * 2 + 1];
        }
        const float mu = s1 * (1.f / (float)DDIM);
        const float var = s2 * (1.f / (float)DDIM) - mu * mu;
        const float rs = rsqrtf(var + LN_EPS_C);
        const float w = ws[WS_W + b * 8 + k];
        sA[b * KEXP + k] = w * rs;            // alpha
        sA[28 + b * KEXP + k] = w * rs * mu;  // alpha*mu
    }
    __syncthreads();
    if (tid < BBATCH) {
        float c = 0.f;
#pragma unroll
        for (int k = 0; k < KEXP; ++k) c += sA[28 + tid * KEXP + k];
        sA[56 + tid] = c;                      // Cb
        sA[60 + tid] = ws[WS_W + tid * 8 + 7]; // wsum
    }
    __syncthreads();

    {
        const float4 g4 = ((const float4*)ln_g)[tid];
        const float4 b4 = ((const float4*)ln_b)[tid];
        const float4* s4p = (const float4*)(ws + WS_S);
#pragma unroll
        for (int b = 0; b < BBATCH; ++b) {
            float4 s = make_float4(0.f, 0.f, 0.f, 0.f);
#pragma unroll
            for (int k = 0; k < KEXP; ++k) {
                const float a = sA[b * KEXP + k];
                float4 v = s4p[(size_t)(b * KEXP + k) * 256 + tid];
                s.x = fmaf(a, v.x, s.x);
                s.y = fmaf(a, v.y, s.y);
                s.z = fmaf(a, v.z, s.z);
                s.w = fmaf(a, v.w, s.w);
            }
            const float C = sA[56 + b], wsum = sA[60 + b];
            float4 o;
            o.x = g4.x * (s.x - C) + b4.x * wsum;
            o.y = g4.y * (s.y - C) + b4.y * wsum;
            o.z = g4.z * (s.z - C) + b4.z * wsum;
            o.w = g4.w * (s.w - C) + b4.w * wsum;
            sB[b * 256 + tid] = o;
        }
    }
    __syncthreads();

    const int e = cb_idx * 4 + wv;
    const float4* cw4 = (const float4*)(comp_w + (size_t)e * DDIM);
    float acc[BBATCH] = {0.f, 0.f, 0.f, 0.f};
#pragma unroll
    for (int j = 0; j < 4; ++j) {
        float4 c = cw4[j * 64 + lane];
#pragma unroll
        for (int b = 0; b < BBATCH; ++b) acc[b] += dot4(c, sB[b * 256 + j * 64 + lane]);
    }
#pragma unroll
    for (int b = 0; b < BBATCH; ++b)
#pragma unroll
        for (int off = 32; off > 0; off >>= 1)
            acc[b] += __shfl_xor(acc[b], off, 64);
    if (lane == 0) {
        const float cb = comp_b[e];
#pragma unroll
        for (int b = 0; b < BBATCH; ++b)
            out[b * DDIM + e] = acc[b] + cb;
    }
}

// ===================== single fused kernel, 512 blocks =====================
// bid 0..111:   gate chunk(bid) -> wait basis -> sv(bid) -> publish
// bid 112..367: gate chunk(bid) -> wait weights+sv -> comp(bid-112)
// bid 368..399: basis(bid-368) -> publish -> gate chunk(bid)
// bid 400..403: weights(bid-400) -> publish -> gate chunk(bid)
// bid 404..511: gate chunk(bid)
// 512 blocks @ 2/CU = exact co-residency; max 368 waiters < 512 slots -> no deadlock.
__global__ __launch_bounds__(256, 2) void k_mega(const float* __restrict__ h,
                                                 const float* __restrict__ gate_w,
                                                 const float* __restrict__ gate_b,
                                                 const float* __restrict__ U_w,
                                                 const float* __restrict__ V,
                                                 const float* __restrict__ ln_g,
                                                 const float* __restrict__ ln_b,
                                                 const float* __restrict__ comp_w,
                                                 const float* __restrict__ comp_b,
                                                 float* __restrict__ G,
                                                 float* __restrict__ out,
                                                 float* __restrict__ ws) {
    int* flags = (int*)ws;
    const int bid = blockIdx.x;
    const int tid = threadIdx.x;
    const int lane = tid & 63;
    const int wv = tid >> 6;

    __shared__ float sA[512];
    __shared__ float4 sB[1024];

    if (bid < 112) {
        gate_chunk(bid, h, gate_w, gate_b, G, lane, wv);
        wait_flags(flags, FLG_BASIS, 32, tid);
        role_sv(bid, V, ws, sA, sB, tid);
        __syncthreads();
        if (tid == 0) publish(flags, FLG_SV + bid);
    } else if (bid < 368) {
        gate_chunk(bid, h, gate_w, gate_b, G, lane, wv);
        wait_flags(flags, FLG_WGT, 116, tid);   // weights (4) + sv (112)
        role_comp(bid - 112, ws, ln_g, ln_b, comp_w, comp_b, out, sA, sB, tid, lane, wv);
    } else if (bid < 400) {
        role_basis(bid - 368, h, U_w, ws, lane, wv);
        __syncthreads();
        if (tid == 0) publish(flags, FLG_BASIS + (bid - 368));
        gate_chunk(bid, h, gate_w, gate_b, G, lane, wv);
    } else if (bid < 404) {
        role_weights(bid - 400, h, gate_w, gate_b, ws, sA, tid, lane, wv);
        __syncthreads();
        if (tid == 0) publish(flags, FLG_WGT + (bid - 400));
        gate_chunk(bid, h, gate_w, gate_b, G, lane, wv);
    } else {
        gate_chunk(bid, h, gate_w, gate_b, G, lane, wv);
    }
}

extern "C" void kernel_launch(void* const* d_in, const int* in_sizes, int n_in,
                              void* d_out, int out_size, void* d_ws, size_t ws_size,
                              hipStream_t stream) {
    const float* h      = (const float*)d_in[0];
    const float* gate_w = (const float*)d_in[1];
    const float* gate_b = (const float*)d_in[2];
    const float* U_w    = (const float*)d_in[3];
    const float* V      = (const float*)d_in[4];
    const float* ln_g   = (const float*)d_in[5];
    const float* ln_b   = (const float*)d_in[6];
    const float* comp_w = (const float*)d_in[7];
    const float* comp_b = (const float*)d_in[8];

    float* out = (float*)d_out;                 // b: 4*1024 floats
    float* G   = out + BBATCH * DDIM;           // G: 4*2048*7 floats
    float* ws  = (float*)d_ws;

    // zero the write-once flag region (148 flags * 128 B) every call
    hipMemsetAsync(d_ws, 0, FLAG_INTS * sizeof(int), stream);
    k_mega<<<512, 256, 0, stream>>>(h, gate_w, gate_b, U_w, V, ln_g, ln_b,
                                    comp_w, comp_b, G, out, ws);
}

// Round 8
// 28.071 us; speedup vs baseline: 5.5507x; 2.7870x over previous
//
#include <hip/hip_runtime.h>
#include <math.h>

#define KEXP 7
#define DDIM 1024
#define RDIM 128
#define TSEQ 2048
#define BBATCH 4
#define TAU_C 1.2f
#define EPS_C 1e-9f
#define LN_EPS_C 1e-5f

// ws float offsets (sync-free: no flags)
#define WS_S     0                    // s[b][k][1024]      : 28672 floats
#define WS_BASIS 28672                // basis[b][128]      : 512
#define WS_W     (WS_BASIS + 512)     // w[b][8]            : 32
#define WS_PSTAT (WS_W + 32)          // pstat[b][k][16][2] : 896

__device__ __forceinline__ float dot4(float4 a, float4 b) {
    return fmaf(a.x, b.x, fmaf(a.y, b.y, fmaf(a.z, b.z, a.w * b.w)));
}

// ---------------- roles ----------------

// basis: basis[b][r] = h_last . U_w[r], 16 r's per block (idx 0..31)
__device__ __forceinline__ void role_basis(int idx, const float* __restrict__ h,
                                           const float* __restrict__ U_w,
                                           float* __restrict__ ws, int lane, int wv) {
    const int b = idx >> 3;
    const int chunk = idx & 7;
    const float4* h4 = (const float4*)(h + ((size_t)b * TSEQ + (TSEQ - 1)) * DDIM);
    float4 hf[4];
#pragma unroll
    for (int j = 0; j < 4; ++j) hf[j] = h4[j * 64 + lane];
    const int r0 = chunk * 16 + wv * 4;
    float part[4];
#pragma unroll
    for (int rr = 0; rr < 4; ++rr) {
        const float4* u4 = (const float4*)(U_w + (size_t)(r0 + rr) * DDIM);
        float a = 0.f;
#pragma unroll
        for (int j = 0; j < 4; ++j) a += dot4(hf[j], u4[j * 64 + lane]);
        part[rr] = a;
    }
#pragma unroll
    for (int off = 32; off > 0; off >>= 1)
#pragma unroll
        for (int rr = 0; rr < 4; ++rr)
            part[rr] += __shfl_xor(part[rr], off, 64);
    if (lane == 0) {
#pragma unroll
        for (int rr = 0; rr < 4; ++rr)
            ws[WS_BASIS + b * RDIM + r0 + rr] = part[rr];
    }
}

// weights: leftover weights for batch b (sA >= 8 floats of LDS)
__device__ __forceinline__ void role_weights(int b, const float* __restrict__ h,
                                             const float* __restrict__ gate_w,
                                             const float* __restrict__ gate_b,
                                             float* __restrict__ ws, float* sA,
                                             int tid, int lane, int wv) {
    const float4* h4 = (const float4*)(h + ((size_t)b * TSEQ + (TSEQ - 1)) * DDIM);
    for (int e = wv; e < KEXP; e += 4) {
        const float4* gw4 = (const float4*)(gate_w + (size_t)e * DDIM);
        float a = 0.f;
#pragma unroll
        for (int j = 0; j < 4; ++j) a += dot4(h4[j * 64 + lane], gw4[j * 64 + lane]);
#pragma unroll
        for (int off = 32; off > 0; off >>= 1) a += __shfl_xor(a, off, 64);
        if (lane == 0) sA[e] = a + gate_b[e];
    }
    __syncthreads();
    if (tid == 0) {
        float l0[KEXP], m0 = -1e30f;
#pragma unroll
        for (int j = 0; j < KEXP; ++j) { l0[j] = sA[j]; m0 = fmaxf(m0, l0[j]); }
        float es0 = 0.f, g[KEXP];
#pragma unroll
        for (int j = 0; j < KEXP; ++j) { g[j] = expf(l0[j] - m0); es0 += g[j]; }
        const float inv0 = 1.f / es0;
#pragma unroll
        for (int j = 0; j < KEXP; ++j) g[j] *= inv0;
        int i1 = 0;
        for (int j = 1; j < KEXP; ++j) if (g[j] > g[i1]) i1 = j;
        int i2 = -1;
        for (int j = 0; j < KEXP; ++j)
            if (j != i1 && (i2 < 0 || g[j] > g[i2])) i2 = j;
        int i3 = -1;
        for (int j = 0; j < KEXP; ++j)
            if (j != i1 && j != i2 && (i3 < 0 || g[j] > g[i3])) i3 = j;
        int i4 = -1;
        for (int j = 0; j < KEXP; ++j)
            if (j != i1 && j != i2 && j != i3 && (i4 < 0 || g[j] > g[i4])) i4 = j;
        float s = fmaxf(g[i3] + g[i4], EPS_C);
        float p[KEXP];
#pragma unroll
        for (int j = 0; j < KEXP; ++j) p[j] = 0.f;
        p[i3] = g[i3] / s;
        p[i4] = g[i4] / s;
        float l[KEXP], m = -1e30f;
#pragma unroll
        for (int j = 0; j < KEXP; ++j) {
            l[j] = logf(fmaxf(p[j], EPS_C)) * (1.f / TAU_C);
            m = fmaxf(m, l[j]);
        }
        float es = 0.f, w[KEXP];
#pragma unroll
        for (int j = 0; j < KEXP; ++j) { w[j] = expf(l[j] - m); es += w[j]; }
        const float inv = 1.f / es;
        float wsum = 0.f;
#pragma unroll
        for (int j = 0; j < KEXP; ++j) { w[j] *= inv; wsum += w[j]; ws[WS_W + b * 8 + j] = w[j]; }
        ws[WS_W + b * 8 + 7] = wsum;
    }
}

// gate: 2 rows per wave with ILP (loads for both rows in flight together,
// 14 interleaved shuffle-reduce chains). One block = 4 waves = 8 rows.
__device__ __forceinline__ void gate_rows8(int row_base, const float* __restrict__ h,
                                           const float* __restrict__ gate_w,
                                           const float* __restrict__ gate_b,
                                           float* __restrict__ G,
                                           int lane, int wv) {
    const float4* gw4 = (const float4*)gate_w;
    float4 gw[KEXP][4];
#pragma unroll
    for (int k = 0; k < KEXP; ++k)
#pragma unroll
        for (int j = 0; j < 4; ++j)
            gw[k][j] = gw4[k * 256 + j * 64 + lane];
    float gb[KEXP];
#pragma unroll
    for (int k = 0; k < KEXP; ++k) gb[k] = gate_b[k];

    const int r0 = row_base + wv * 2;
    const float4* h40 = (const float4*)(h + (size_t)r0 * DDIM);
    const float4* h41 = (const float4*)(h + (size_t)(r0 + 1) * DDIM);
    float4 hv0[4], hv1[4];
#pragma unroll
    for (int j = 0; j < 4; ++j) hv0[j] = h40[j * 64 + lane];
#pragma unroll
    for (int j = 0; j < 4; ++j) hv1[j] = h41[j * 64 + lane];

    float a0[KEXP], a1[KEXP];
#pragma unroll
    for (int k = 0; k < KEXP; ++k) { a0[k] = 0.f; a1[k] = 0.f; }
#pragma unroll
    for (int j = 0; j < 4; ++j) {
#pragma unroll
        for (int k = 0; k < KEXP; ++k) {
            a0[k] += dot4(hv0[j], gw[k][j]);
            a1[k] += dot4(hv1[j], gw[k][j]);
        }
    }
#pragma unroll
    for (int off = 32; off > 0; off >>= 1) {
#pragma unroll
        for (int k = 0; k < KEXP; ++k) a0[k] += __shfl_xor(a0[k], off, 64);
#pragma unroll
        for (int k = 0; k < KEXP; ++k) a1[k] += __shfl_xor(a1[k], off, 64);
    }
    float m0 = -1e30f, m1 = -1e30f;
#pragma unroll
    for (int k = 0; k < KEXP; ++k) {
        a0[k] += gb[k]; m0 = fmaxf(m0, a0[k]);
        a1[k] += gb[k]; m1 = fmaxf(m1, a1[k]);
    }
    float e0[KEXP], e1[KEXP], s0 = 0.f, s1 = 0.f;
#pragma unroll
    for (int k = 0; k < KEXP; ++k) {
        e0[k] = expf(a0[k] - m0); s0 += e0[k];
        e1[k] = expf(a1[k] - m1); s1 += e1[k];
    }
    const float i0 = 1.f / s0, i1 = 1.f / s1;
    if (lane == 0) {
#pragma unroll
        for (int k = 0; k < KEXP; ++k) G[r0 * KEXP + k] = e0[k] * i0;
#pragma unroll
        for (int k = 0; k < KEXP; ++k) G[(r0 + 1) * KEXP + k] = e1[k] * i1;
    }
}

// sv: s[b][k][64-d chunk] for all b, + partial LN stats. Needs sA[512], sB[1024].
__device__ __forceinline__ void role_sv(int idx, const float* __restrict__ V,
                                        float* __restrict__ ws, float* sA, float4* sB,
                                        int tid) {
    const int k = idx >> 4;
    const int chunk = idx & 15;
    const int col = tid & 15;
    const int rc = tid >> 4;

    sA[tid] = ws[WS_BASIS + tid];
    sA[tid + 256] = ws[WS_BASIS + tid + 256];
    __syncthreads();

    const float4* V4 = (const float4*)(V + (size_t)k * RDIM * DDIM);
    float4 acc[BBATCH];
#pragma unroll
    for (int b = 0; b < BBATCH; ++b) acc[b] = make_float4(0.f, 0.f, 0.f, 0.f);
#pragma unroll
    for (int rr = 0; rr < 8; ++rr) {
        const int r = rc * 8 + rr;
        float4 v = V4[(size_t)r * 256 + chunk * 16 + col];
#pragma unroll
        for (int b = 0; b < BBATCH; ++b) {
            const float br = sA[b * RDIM + r];
            acc[b].x = fmaf(br, v.x, acc[b].x);
            acc[b].y = fmaf(br, v.y, acc[b].y);
            acc[b].z = fmaf(br, v.z, acc[b].z);
            acc[b].w = fmaf(br, v.w, acc[b].w);
        }
    }
#pragma unroll
    for (int b = 0; b < BBATCH; ++b) sB[(rc * 4 + b) * 16 + col] = acc[b];
    __syncthreads();

    if (tid < 64) {
        const int b = tid >> 4;
        const int c = tid & 15;
        float4 s4 = make_float4(0.f, 0.f, 0.f, 0.f);
#pragma unroll
        for (int q = 0; q < 16; ++q) {
            float4 p = sB[(q * 4 + b) * 16 + c];
            s4.x += p.x; s4.y += p.y; s4.z += p.z; s4.w += p.w;
        }
        ((float4*)(ws + WS_S))[(size_t)(b * KEXP + k) * 256 + chunk * 16 + c] = s4;
        float p1 = s4.x + s4.y + s4.z + s4.w;
        float p2 = dot4(s4, s4);
#pragma unroll
        for (int off = 8; off > 0; off >>= 1) {
            p1 += __shfl_xor(p1, off, 64);
            p2 += __shfl_xor(p2, off, 64);
        }
        if (c == 0) {
            ws[WS_PSTAT + ((b * KEXP + k) * 16 + chunk) * 2 + 0] = p1;
            ws[WS_PSTAT + ((b * KEXP + k) * 16 + chunk) * 2 + 1] = p2;
        }
    }
}

// comp: finalize LN stats, bvec in LDS, comp matvec for e = cb_idx*4 + wv.
__device__ __forceinline__ void role_comp(int cb_idx, const float* __restrict__ ws,
                                          const float* __restrict__ ln_g,
                                          const float* __restrict__ ln_b,
                                          const float* __restrict__ comp_w,
                                          const float* __restrict__ comp_b,
                                          float* __restrict__ out,
                                          float* sA, float4* sB,
                                          int tid, int lane, int wv) {
    if (tid < BBATCH * KEXP) {
        const int b = tid / KEXP;
        const int k = tid % KEXP;
        float s1 = 0.f, s2 = 0.f;
#pragma unroll
        for (int c = 0; c < 16; ++c) {
            s1 += ws[WS_PSTAT + ((b * KEXP + k) * 16 + c) * 2 + 0];
            s2 += ws[WS_PSTAT + ((b * KEXP + k) * 16 + c) * 2 + 1];
        }
        const float mu = s1 * (1.f / (float)DDIM);
        const float var = s2 * (1.f / (float)DDIM) - mu * mu;
        const float rs = rsqrtf(var + LN_EPS_C);
        const float w = ws[WS_W + b * 8 + k];
        sA[b * KEXP + k] = w * rs;            // alpha
        sA[28 + b * KEXP + k] = w * rs * mu;  // alpha*mu
    }
    __syncthreads();
    if (tid < BBATCH) {
        float c = 0.f;
#pragma unroll
        for (int k = 0; k < KEXP; ++k) c += sA[28 + tid * KEXP + k];
        sA[56 + tid] = c;                      // Cb
        sA[60 + tid] = ws[WS_W + tid * 8 + 7]; // wsum
    }
    __syncthreads();

    {
        const float4 g4 = ((const float4*)ln_g)[tid];
        const float4 b4 = ((const float4*)ln_b)[tid];
        const float4* s4p = (const float4*)(ws + WS_S);
#pragma unroll
        for (int b = 0; b < BBATCH; ++b) {
            float4 s = make_float4(0.f, 0.f, 0.f, 0.f);
#pragma unroll
            for (int k = 0; k < KEXP; ++k) {
                const float a = sA[b * KEXP + k];
                float4 v = s4p[(size_t)(b * KEXP + k) * 256 + tid];
                s.x = fmaf(a, v.x, s.x);
                s.y = fmaf(a, v.y, s.y);
                s.z = fmaf(a, v.z, s.z);
                s.w = fmaf(a, v.w, s.w);
            }
            const float C = sA[56 + b], wsum = sA[60 + b];
            float4 o;
            o.x = g4.x * (s.x - C) + b4.x * wsum;
            o.y = g4.y * (s.y - C) + b4.y * wsum;
            o.z = g4.z * (s.z - C) + b4.z * wsum;
            o.w = g4.w * (s.w - C) + b4.w * wsum;
            sB[b * 256 + tid] = o;
        }
    }
    __syncthreads();

    const int e = cb_idx * 4 + wv;
    const float4* cw4 = (const float4*)(comp_w + (size_t)e * DDIM);
    float acc[BBATCH] = {0.f, 0.f, 0.f, 0.f};
#pragma unroll
    for (int j = 0; j < 4; ++j) {
        float4 c = cw4[j * 64 + lane];
#pragma unroll
        for (int b = 0; b < BBATCH; ++b) acc[b] += dot4(c, sB[b * 256 + j * 64 + lane]);
    }
#pragma unroll
    for (int b = 0; b < BBATCH; ++b)
#pragma unroll
        for (int off = 32; off > 0; off >>= 1)
            acc[b] += __shfl_xor(acc[b], off, 64);
    if (lane == 0) {
        const float cb = comp_b[e];
#pragma unroll
        for (int b = 0; b < BBATCH; ++b)
            out[b * DDIM + e] = acc[b] + cb;
    }
}

// ===================== stage 1: prep + gate rows 0..2047 =====================
__global__ __launch_bounds__(256) void k_pre(const float* __restrict__ h,
                                             const float* __restrict__ gate_w,
                                             const float* __restrict__ gate_b,
                                             const float* __restrict__ U_w,
                                             float* __restrict__ G,
                                             float* __restrict__ ws) {
    __shared__ float sA[8];
    const int bid = blockIdx.x;
    const int tid = threadIdx.x;
    const int lane = tid & 63;
    const int wv = tid >> 6;
    if (bid < 32)       role_basis(bid, h, U_w, ws, lane, wv);
    else if (bid < 36)  role_weights(bid - 32, h, gate_w, gate_b, ws, sA, tid, lane, wv);
    else                gate_rows8((bid - 36) * 8, h, gate_w, gate_b, G, lane, wv);
}

// ===================== stage 2: sv + gate rows 2048..8191 =====================
__global__ __launch_bounds__(256) void k_main(const float* __restrict__ h,
                                              const float* __restrict__ gate_w,
                                              const float* __restrict__ gate_b,
                                              const float* __restrict__ V,
                                              float* __restrict__ G,
                                              float* __restrict__ ws) {
    __shared__ float sA[512];
    __shared__ float4 sB[1024];
    const int bid = blockIdx.x;
    const int tid = threadIdx.x;
    const int lane = tid & 63;
    const int wv = tid >> 6;
    if (bid < 112) role_sv(bid, V, ws, sA, sB, tid);
    else           gate_rows8(2048 + (bid - 112) * 8, h, gate_w, gate_b, G, lane, wv);
}

// ===================== stage 3: comp =====================
__global__ __launch_bounds__(256) void k_comp2(const float* __restrict__ ws,
                                               const float* __restrict__ ln_g,
                                               const float* __restrict__ ln_b,
                                               const float* __restrict__ comp_w,
                                               const float* __restrict__ comp_b,
                                               float* __restrict__ out) {
    __shared__ float sA[512];
    __shared__ float4 sB[1024];
    const int tid = threadIdx.x;
    const int lane = tid & 63;
    const int wv = tid >> 6;
    role_comp(blockIdx.x, ws, ln_g, ln_b, comp_w, comp_b, out, sA, sB, tid, lane, wv);
}

extern "C" void kernel_launch(void* const* d_in, const int* in_sizes, int n_in,
                              void* d_out, int out_size, void* d_ws, size_t ws_size,
                              hipStream_t stream) {
    const float* h      = (const float*)d_in[0];
    const float* gate_w = (const float*)d_in[1];
    const float* gate_b = (const float*)d_in[2];
    const float* U_w    = (const float*)d_in[3];
    const float* V      = (const float*)d_in[4];
    const float* ln_g   = (const float*)d_in[5];
    const float* ln_b   = (const float*)d_in[6];
    const float* comp_w = (const float*)d_in[7];
    const float* comp_b = (const float*)d_in[8];

    float* out = (float*)d_out;                 // b: 4*1024 floats
    float* G   = out + BBATCH * DDIM;           // G: 4*2048*7 floats
    float* ws  = (float*)d_ws;

    k_pre<<<292, 256, 0, stream>>>(h, gate_w, gate_b, U_w, G, ws);
    k_main<<<880, 256, 0, stream>>>(h, gate_w, gate_b, V, G, ws);
    k_comp2<<<256, 256, 0, stream>>>(ws, ln_g, ln_b, comp_w, comp_b, out);
}

// Round 11
// 25.801 us; speedup vs baseline: 6.0390x; 1.0880x over previous
//
#include <hip/hip_runtime.h>
#include <math.h>

#define KEXP 7
#define DDIM 1024
#define RDIM 128
#define TSEQ 2048
#define BBATCH 4
#define TAU_C 1.2f
#define EPS_C 1e-9f
#define LN_EPS_C 1e-5f

// ws float offsets (sync-free)
#define WS_S     0                    // s[b][k][1024]      : 28672 floats
#define WS_BASIS 28672                // basis[b][128]      : 512
#define WS_W     (WS_BASIS + 512)     // w[b][8]            : 32
#define WS_PSTAT (WS_W + 32)          // pstat[b][k][16][2] : 896

__device__ __forceinline__ float dot4(float4 a, float4 b) {
    return fmaf(a.x, b.x, fmaf(a.y, b.y, fmaf(a.z, b.z, a.w * b.w)));
}

// ---------------- roles ----------------

// basis: basis[b][r] = h_last . U_w[r], 16 r's per block (idx 0..31)
__device__ __forceinline__ void role_basis(int idx, const float* __restrict__ h,
                                           const float* __restrict__ U_w,
                                           float* __restrict__ ws, int lane, int wv) {
    const int b = idx >> 3;
    const int chunk = idx & 7;
    const float4* h4 = (const float4*)(h + ((size_t)b * TSEQ + (TSEQ - 1)) * DDIM);
    float4 hf[4];
#pragma unroll
    for (int j = 0; j < 4; ++j) hf[j] = h4[j * 64 + lane];
    const int r0 = chunk * 16 + wv * 4;
    float part[4];
#pragma unroll
    for (int rr = 0; rr < 4; ++rr) {
        const float4* u4 = (const float4*)(U_w + (size_t)(r0 + rr) * DDIM);
        float a = 0.f;
#pragma unroll
        for (int j = 0; j < 4; ++j) a += dot4(hf[j], u4[j * 64 + lane]);
        part[rr] = a;
    }
#pragma unroll
    for (int off = 32; off > 0; off >>= 1)
#pragma unroll
        for (int rr = 0; rr < 4; ++rr)
            part[rr] += __shfl_xor(part[rr], off, 64);
    if (lane == 0) {
#pragma unroll
        for (int rr = 0; rr < 4; ++rr)
            ws[WS_BASIS + b * RDIM + r0 + rr] = part[rr];
    }
}

// weights: leftover weights for batch b (sA >= 8 floats of LDS)
__device__ __forceinline__ void role_weights(int b, const float* __restrict__ h,
                                             const float* __restrict__ gate_w,
                                             const float* __restrict__ gate_b,
                                             float* __restrict__ ws, float* sA,
                                             int tid, int lane, int wv) {
    const float4* h4 = (const float4*)(h + ((size_t)b * TSEQ + (TSEQ - 1)) * DDIM);
    for (int e = wv; e < KEXP; e += 4) {
        const float4* gw4 = (const float4*)(gate_w + (size_t)e * DDIM);
        float a = 0.f;
#pragma unroll
        for (int j = 0; j < 4; ++j) a += dot4(h4[j * 64 + lane], gw4[j * 64 + lane]);
#pragma unroll
        for (int off = 32; off > 0; off >>= 1) a += __shfl_xor(a, off, 64);
        if (lane == 0) sA[e] = a + gate_b[e];
    }
    __syncthreads();
    if (tid == 0) {
        float l0[KEXP], m0 = -1e30f;
#pragma unroll
        for (int j = 0; j < KEXP; ++j) { l0[j] = sA[j]; m0 = fmaxf(m0, l0[j]); }
        float es0 = 0.f, g[KEXP];
#pragma unroll
        for (int j = 0; j < KEXP; ++j) { g[j] = expf(l0[j] - m0); es0 += g[j]; }
        const float inv0 = 1.f / es0;
#pragma unroll
        for (int j = 0; j < KEXP; ++j) g[j] *= inv0;
        int i1 = 0;
        for (int j = 1; j < KEXP; ++j) if (g[j] > g[i1]) i1 = j;
        int i2 = -1;
        for (int j = 0; j < KEXP; ++j)
            if (j != i1 && (i2 < 0 || g[j] > g[i2])) i2 = j;
        int i3 = -1;
        for (int j = 0; j < KEXP; ++j)
            if (j != i1 && j != i2 && (i3 < 0 || g[j] > g[i3])) i3 = j;
        int i4 = -1;
        for (int j = 0; j < KEXP; ++j)
            if (j != i1 && j != i2 && j != i3 && (i4 < 0 || g[j] > g[i4])) i4 = j;
        float s = fmaxf(g[i3] + g[i4], EPS_C);
        float p[KEXP];
#pragma unroll
        for (int j = 0; j < KEXP; ++j) p[j] = 0.f;
        p[i3] = g[i3] / s;
        p[i4] = g[i4] / s;
        float l[KEXP], m = -1e30f;
#pragma unroll
        for (int j = 0; j < KEXP; ++j) {
            l[j] = logf(fmaxf(p[j], EPS_C)) * (1.f / TAU_C);
            m = fmaxf(m, l[j]);
        }
        float es = 0.f, w[KEXP];
#pragma unroll
        for (int j = 0; j < KEXP; ++j) { w[j] = expf(l[j] - m); es += w[j]; }
        const float inv = 1.f / es;
        float wsum = 0.f;
#pragma unroll
        for (int j = 0; j < KEXP; ++j) { w[j] *= inv; wsum += w[j]; ws[WS_W + b * 8 + j] = w[j]; }
        ws[WS_W + b * 8 + 7] = wsum;
    }
}

// one 16-row gate chunk (R3-proven): 4 rows/wave serial, gw register-staged.
__device__ __forceinline__ void gate_chunk(int c, const float* __restrict__ h,
                                           const float* __restrict__ gate_w,
                                           const float* __restrict__ gate_b,
                                           float* __restrict__ G,
                                           int lane, int wv) {
    const float4* gw4 = (const float4*)gate_w;
    float4 gw[KEXP][4];
#pragma unroll
    for (int k = 0; k < KEXP; ++k)
#pragma unroll
        for (int j = 0; j < 4; ++j)
            gw[k][j] = gw4[k * 256 + j * 64 + lane];
    float gb[KEXP];
#pragma unroll
    for (int k = 0; k < KEXP; ++k) gb[k] = gate_b[k];

    const int row0 = c * 16 + wv * 4;
#pragma unroll
    for (int r = 0; r < 4; ++r) {
        const int row = row0 + r;
        const float4* h4 = (const float4*)(h + (size_t)row * DDIM);
        float acc[KEXP];
#pragma unroll
        for (int k = 0; k < KEXP; ++k) acc[k] = 0.f;
#pragma unroll
        for (int j = 0; j < 4; ++j) {
            float4 hv = h4[j * 64 + lane];
#pragma unroll
            for (int k = 0; k < KEXP; ++k) {
                acc[k] = fmaf(hv.x, gw[k][j].x, acc[k]);
                acc[k] = fmaf(hv.y, gw[k][j].y, acc[k]);
                acc[k] = fmaf(hv.z, gw[k][j].z, acc[k]);
                acc[k] = fmaf(hv.w, gw[k][j].w, acc[k]);
            }
        }
#pragma unroll
        for (int k = 0; k < KEXP; ++k) {
#pragma unroll
            for (int off = 32; off > 0; off >>= 1)
                acc[k] += __shfl_xor(acc[k], off, 64);
        }
        float m = -1e30f;
#pragma unroll
        for (int k = 0; k < KEXP; ++k) { acc[k] += gb[k]; m = fmaxf(m, acc[k]); }
        float e[KEXP];
        float s = 0.f;
#pragma unroll
        for (int k = 0; k < KEXP; ++k) { e[k] = expf(acc[k] - m); s += e[k]; }
        const float inv = 1.f / s;
        if (lane == 0) {
#pragma unroll
            for (int k = 0; k < KEXP; ++k) G[row * KEXP + k] = e[k] * inv;
        }
    }
}

// sv: s[b][k][64-d chunk] for all b, + partial LN stats. Needs sA[512], sB[1024].
__device__ __forceinline__ void role_sv(int idx, const float* __restrict__ V,
                                        float* __restrict__ ws, float* sA, float4* sB,
                                        int tid) {
    const int k = idx >> 4;
    const int chunk = idx & 15;
    const int col = tid & 15;
    const int rc = tid >> 4;

    sA[tid] = ws[WS_BASIS + tid];
    sA[tid + 256] = ws[WS_BASIS + tid + 256];
    __syncthreads();

    const float4* V4 = (const float4*)(V + (size_t)k * RDIM * DDIM);
    float4 acc[BBATCH];
#pragma unroll
    for (int b = 0; b < BBATCH; ++b) acc[b] = make_float4(0.f, 0.f, 0.f, 0.f);
#pragma unroll
    for (int rr = 0; rr < 8; ++rr) {
        const int r = rc * 8 + rr;
        float4 v = V4[(size_t)r * 256 + chunk * 16 + col];
#pragma unroll
        for (int b = 0; b < BBATCH; ++b) {
            const float br = sA[b * RDIM + r];
            acc[b].x = fmaf(br, v.x, acc[b].x);
            acc[b].y = fmaf(br, v.y, acc[b].y);
            acc[b].z = fmaf(br, v.z, acc[b].z);
            acc[b].w = fmaf(br, v.w, acc[b].w);
        }
    }
#pragma unroll
    for (int b = 0; b < BBATCH; ++b) sB[(rc * 4 + b) * 16 + col] = acc[b];
    __syncthreads();

    if (tid < 64) {
        const int b = tid >> 4;
        const int c = tid & 15;
        float4 s4 = make_float4(0.f, 0.f, 0.f, 0.f);
#pragma unroll
        for (int q = 0; q < 16; ++q) {
            float4 p = sB[(q * 4 + b) * 16 + c];
            s4.x += p.x; s4.y += p.y; s4.z += p.z; s4.w += p.w;
        }
        ((float4*)(ws + WS_S))[(size_t)(b * KEXP + k) * 256 + chunk * 16 + c] = s4;
        float p1 = s4.x + s4.y + s4.z + s4.w;
        float p2 = dot4(s4, s4);
#pragma unroll
        for (int off = 8; off > 0; off >>= 1) {
            p1 += __shfl_xor(p1, off, 64);
            p2 += __shfl_xor(p2, off, 64);
        }
        if (c == 0) {
            ws[WS_PSTAT + ((b * KEXP + k) * 16 + chunk) * 2 + 0] = p1;
            ws[WS_PSTAT + ((b * KEXP + k) * 16 + chunk) * 2 + 1] = p2;
        }
    }
}

// comp: finalize LN stats, bvec in LDS, comp matvec for e = cb_idx*4 + wv.
__device__ __forceinline__ void role_comp(int cb_idx, const float* __restrict__ ws,
                                          const float* __restrict__ ln_g,
                                          const float* __restrict__ ln_b,
                                          const float* __restrict__ comp_w,
                                          const float* __restrict__ comp_b,
                                          float* __restrict__ out,
                                          float* sA, float4* sB,
                                          int tid, int lane, int wv) {
    if (tid < BBATCH * KEXP) {
        const int b = tid / KEXP;
        const int k = tid % KEXP;
        float s1 = 0.f, s2 = 0.f;
#pragma unroll
        for (int c = 0; c < 16; ++c) {
            s1 += ws[WS_PSTAT + ((b * KEXP + k) * 16 + c) * 2 + 0];
            s2 += ws[WS_PSTAT + ((b * KEXP + k) * 16 + c) * 2 + 1];
        }
        const float mu = s1 * (1.f / (float)DDIM);
        const float var = s2 * (1.f / (float)DDIM) - mu * mu;
        const float rs = rsqrtf(var + LN_EPS_C);
        const float w = ws[WS_W + b * 8 + k];
        sA[b * KEXP + k] = w * rs;            // alpha
        sA[28 + b * KEXP + k] = w * rs * mu;  // alpha*mu
    }
    __syncthreads();
    if (tid < BBATCH) {
        float c = 0.f;
#pragma unroll
        for (int k = 0; k < KEXP; ++k) c += sA[28 + tid * KEXP + k];
        sA[56 + tid] = c;                      // Cb
        sA[60 + tid] = ws[WS_W + tid * 8 + 7]; // wsum
    }
    __syncthreads();

    {
        const float4 g4 = ((const float4*)ln_g)[tid];
        const float4 b4 = ((const float4*)ln_b)[tid];
        const float4* s4p = (const float4*)(ws + WS_S);
#pragma unroll
        for (int b = 0; b < BBATCH; ++b) {
            float4 s = make_float4(0.f, 0.f, 0.f, 0.f);
#pragma unroll
            for (int k = 0; k < KEXP; ++k) {
                const float a = sA[b * KEXP + k];
                float4 v = s4p[(size_t)(b * KEXP + k) * 256 + tid];
                s.x = fmaf(a, v.x, s.x);
                s.y = fmaf(a, v.y, s.y);
                s.z = fmaf(a, v.z, s.z);
                s.w = fmaf(a, v.w, s.w);
            }
            const float C = sA[56 + b], wsum = sA[60 + b];
            float4 o;
            o.x = g4.x * (s.x - C) + b4.x * wsum;
            o.y = g4.y * (s.y - C) + b4.y * wsum;
            o.z = g4.z * (s.z - C) + b4.z * wsum;
            o.w = g4.w * (s.w - C) + b4.w * wsum;
            sB[b * 256 + tid] = o;
        }
    }
    __syncthreads();

    const int e = cb_idx * 4 + wv;
    const float4* cw4 = (const float4*)(comp_w + (size_t)e * DDIM);
    float acc[BBATCH] = {0.f, 0.f, 0.f, 0.f};
#pragma unroll
    for (int j = 0; j < 4; ++j) {
        float4 c = cw4[j * 64 + lane];
#pragma unroll
        for (int b = 0; b < BBATCH; ++b) acc[b] += dot4(c, sB[b * 256 + j * 64 + lane]);
    }
#pragma unroll
    for (int b = 0; b < BBATCH; ++b)
#pragma unroll
        for (int off = 32; off > 0; off >>= 1)
            acc[b] += __shfl_xor(acc[b], off, 64);
    if (lane == 0) {
        const float cb = comp_b[e];
#pragma unroll
        for (int b = 0; b < BBATCH; ++b)
            out[b * DDIM + e] = acc[b] + cb;
    }
}

// ===================== stage 1: prep (basis + weights), 36 blocks ============
__global__ __launch_bounds__(256) void k_prep(const float* __restrict__ h,
                                              const float* __restrict__ gate_w,
                                              const float* __restrict__ gate_b,
                                              const float* __restrict__ U_w,
                                              float* __restrict__ ws) {
    __shared__ float sA[8];
    const int tid = threadIdx.x;
    const int lane = tid & 63;
    const int wv = tid >> 6;
    if (blockIdx.x < 32) role_basis(blockIdx.x, h, U_w, ws, lane, wv);
    else                 role_weights(blockIdx.x - 32, h, gate_w, gate_b, ws, sA, tid, lane, wv);
}

// ===================== stage 2: sv (112) + gate all rows (512), 624 blocks ===
__global__ __launch_bounds__(256) void k_main(const float* __restrict__ h,
                                              const float* __restrict__ gate_w,
                                              const float* __restrict__ gate_b,
                                              const float* __restrict__ V,
                                              float* __restrict__ G,
                                              float* __restrict__ ws) {
    __shared__ float sA[512];
    __shared__ float4 sB[1024];
    const int bid = blockIdx.x;
    const int tid = threadIdx.x;
    const int lane = tid & 63;
    const int wv = tid >> 6;
    if (bid < 112) role_sv(bid, V, ws, sA, sB, tid);
    else           gate_chunk(bid - 112, h, gate_w, gate_b, G, lane, wv);
}

// ===================== stage 3: comp, 256 blocks =============================
__global__ __launch_bounds__(256) void k_comp2(const float* __restrict__ ws,
                                               const float* __restrict__ ln_g,
                                               const float* __restrict__ ln_b,
                                               const float* __restrict__ comp_w,
                                               const float* __restrict__ comp_b,
                                               float* __restrict__ out) {
    __shared__ float sA[512];
    __shared__ float4 sB[1024];
    const int tid = threadIdx.x;
    const int lane = tid & 63;
    const int wv = tid >> 6;
    role_comp(blockIdx.x, ws, ln_g, ln_b, comp_w, comp_b, out, sA, sB, tid, lane, wv);
}

extern "C" void kernel_launch(void* const* d_in, const int* in_sizes, int n_in,
                              void* d_out, int out_size, void* d_ws, size_t ws_size,
                              hipStream_t stream) {
    const float* h      = (const float*)d_in[0];
    const float* gate_w = (const float*)d_in[1];
    const float* gate_b = (const float*)d_in[2];
    const float* U_w    = (const float*)d_in[3];
    const float* V      = (const float*)d_in[4];
    const float* ln_g   = (const float*)d_in[5];
    const float* ln_b   = (const float*)d_in[6];
    const float* comp_w = (const float*)d_in[7];
    const float* comp_b = (const float*)d_in[8];

    float* out = (float*)d_out;                 // b: 4*1024 floats
    float* G   = out + BBATCH * DDIM;           // G: 4*2048*7 floats
    float* ws  = (float*)d_ws;

    k_prep<<<36, 256, 0, stream>>>(h, gate_w, gate_b, U_w, ws);
    k_main<<<624, 256, 0, stream>>>(h, gate_w, gate_b, V, G, ws);
    k_comp2<<<256, 256, 0, stream>>>(ws, ln_g, ln_b, comp_w, comp_b, out);
}